// Round 1
// baseline (342.176 us; speedup 1.0000x reference)
//
#include <hip/hip_runtime.h>

// Arnold cat, 7 iterations fused: out[b,i,j,:] = in[b, (239i+169j)%1024, (338i+239j)%1024, :]
// Tile re-proportioned 64x64 -> 256x16 (same 48KB LDS, 3 blocks/CU):
//   read : segment = 256 px = 3072 B contiguous per (c), loaded 16B/lane (dwordx4)
//          -> 4x longer DRAM runs, 6 VMEM instrs/thread (was 8).
//   write: runs shrink to 16 px = 192 B, but adjacent-c0 tiles of a strip produce
//          j-contiguous runs into the SAME output rows; strip->XCD swizzle keeps
//          them on one L2 so lines merge before eviction.
// LDS holds each segment as raw bytes (pitch 3120 = 16B-aligned for b128 writes;
// phase-2 12B reads at 780*dc+3*rl dwords = exactly 2 lanes/bank = free).
// Index math (R=169c, col=r+239c ; i=169r, j=c+41i) inherited from the
// absmax=0-verified 64x64 kernel; only the tiling/copy units changed.

#define NDIM    1024
#define MASKN   1023
#define ROWB    12288            // bytes per image row (1024 px * 12 B)
#define TR      256              // tile extent along r (read-run length, px)
#define TC      16               // tile extent along c (write-run length, px)
#define PITCHB  3120             // LDS bytes per segment: 3072 + 48 pad; %16==0

typedef float f4u __attribute__((ext_vector_type(4), aligned(4)));

__global__ __launch_bounds__(512) void arnold_cat7_kernel(
    const float* __restrict__ in, float* __restrict__ out) {
    __shared__ alignas(16) unsigned char lds[TC * PITCHB];  // 49920 B -> 3 blocks/CU

    // ---- block swizzle: B -> (batch, r0, c0); same-(batch,r0) strips on one XCD,
    // c0 fastest-varying so same-strip tiles are temporally adjacent on that XCD.
    const int B     = blockIdx.x;             // 0..4095
    const int xcd   = B & 7;
    const int q     = B >> 3;                 // 0..511
    const int c0i   = q & 63;
    const int strip = ((q >> 6) << 3) | xcd;  // 0..63
    const int bimg  = strip >> 2;             // 0..15
    const int r0    = (strip & 3) << 8;       // 0,256,512,768
    const int c0    = c0i << 4;

    const int t    = threadIdx.x;             // 0..511
    const int w    = t >> 6;                  // wave id 0..7
    const int lane = t & 63;

    const unsigned char* __restrict__ inb =
        (const unsigned char*)in + (size_t)bimg * (size_t)(NDIM * ROWB);
    float* __restrict__ outb = out + (size_t)bimg * (size_t)(NDIM * NDIM * 3);

    // ---- phase 1: global -> LDS. 16 segments x 3072B; each wave owns a 1024B
    // window (g = seg*3 + woff). Fast path: one dwordx4 per lane. A window that
    // straddles the circular row boundary (~8% of waves) falls back to 4B loads.
#pragma unroll
    for (int k = 0; k < 6; ++k) {
        const int g    = w + 8 * k;           // 0..47, each exactly once per block
        const int seg  = g / 3;               // 0..15  (wave-uniform)
        const int woff = g - 3 * seg;         // 0..2
        const int c    = c0 + seg;
        const int R    = (169 * c) & MASKN;
        const int col0 = (r0 + 239 * c) & MASKN;
        const unsigned wb = (unsigned)col0 * 12u + (unsigned)woff * 1024u;
        const unsigned char* __restrict__ rowp = inb + (unsigned)R * (unsigned)ROWB;
        unsigned char* __restrict__ dwin = &lds[seg * PITCHB + woff * 1024];

        if (wb < (unsigned)ROWB && wb + 1024u > (unsigned)ROWB) {
            // window contains the row wrap: dword-granular (always 4B-safe)
#pragma unroll
            for (int qq = 0; qq < 4; ++qq) {
                const unsigned o  = wb + (unsigned)(lane * 4 + qq * 256);
                const unsigned oo = (o >= (unsigned)ROWB) ? o - (unsigned)ROWB : o;
                *(float*)(dwin + lane * 4 + qq * 256) = *(const float*)(rowp + oo);
            }
        } else {
            const unsigned o  = wb + (unsigned)(lane * 16);
            const unsigned oo = (o >= (unsigned)ROWB) ? o - (unsigned)ROWB : o;
            *(f4u*)(dwin + lane * 16) = *(const f4u*)(rowp + oo);
        }
    }
    __syncthreads();

    // ---- phase 2: LDS -> global, per-pixel 12B lanes (unchanged structure).
    // Wave = 4 output rows x 16 px: four 192B runs; adjacent-c0 tiles extend the
    // same rows contiguously -> L2 line merge on this XCD.
#pragma unroll
    for (int k = 0; k < 8; ++k) {
        const int p  = t + 512 * k;           // 0..4095
        const int rl = p >> 4;                // 0..255
        const int dc = p & 15;
        const int i  = (169 * (r0 + rl)) & MASKN;
        const int j  = (c0 + dc + 41 * i) & MASKN;
        const float* __restrict__ s = (const float*)&lds[dc * PITCHB + rl * 12];
        float* __restrict__ d = outb + (unsigned)(i * NDIM + j) * 3u;
        d[0] = s[0];
        d[1] = s[1];
        d[2] = s[2];
    }
}

extern "C" void kernel_launch(void* const* d_in, const int* in_sizes, int n_in,
                              void* d_out, int out_size, void* d_ws, size_t ws_size,
                              hipStream_t stream) {
    (void)in_sizes; (void)n_in; (void)d_ws; (void)ws_size; (void)out_size;
    const float* in = (const float*)d_in[0];
    float* out      = (float*)d_out;
    dim3 grid(4096, 1, 1);   // 16 batches x 4 r0-strips x 64 c0-tiles
    dim3 block(512, 1, 1);
    hipLaunchKernelGGL(arnold_cat7_kernel, grid, block, 0, stream, in, out);
}

// Round 2
// 335.569 us; speedup vs baseline: 1.0197x; 1.0197x over previous
//
#include <hip/hip_runtime.h>

// Arnold cat, 7 iterations fused: out[b,i,j,:] = in[b, (239i+169j)%1024, (338i+239j)%1024, :]
// Same 64x64 tile, same LDS byte-image (pitch 772B = 193 dwords), same XCD
// swizzle as the absmax=0-verified round-0 kernel. Change: both global phases
// now copy raw 16B chunks (48 chunks per 768B run) instead of 12B pixels as
// 3 dword ops -> one dwordx4 per chunk, eliminating the 3x per-instruction
// L2 line-touch amplification that was invariant across rounds 0-1.
//   phase 1: chunk=(seg,off): global_load_dwordx4 from row R(seg) bytes
//            [wb+off*16), stored to lds[seg*772 + off*16) (4 dword writes).
//   phase 2: chunk=(run r,off): 4 dword gathers lds[cp*772 + r*12 + e]
//            (cp = byte/12 via magic mul), one global_store_dwordx4 to row i.
// Runs that wrap mod 12288 fall back to per-dword ops for the straddling
// chunk only (<=2 lanes/wave).

#define NDIM    1024
#define MASKN   1023
#define ROWB    12288            // bytes per image row (1024 px * 12 B)
#define PITCHB  772              // LDS bytes per segment: 768 + 4 (193 dwords, odd)

typedef float f4u __attribute__((ext_vector_type(4), aligned(4)));

__global__ __launch_bounds__(512) void arnold_cat7_kernel(
    const float* __restrict__ in, float* __restrict__ out) {
    __shared__ alignas(16) unsigned char lds[64 * PITCHB];  // 49408 B -> 3 blocks/CU

    // ---- block swizzle (identical to round 0): B -> (batch, r0, c0);
    // same-(batch,r0) strips pinned to one XCD so partial lines merge in its L2.
    const int B     = blockIdx.x;        // 0..4095
    const int xcd   = B & 7;
    const int q     = B >> 3;            // 0..511
    const int c0i   = q & 15;
    const int strip = ((q >> 4) << 3) | xcd;  // 0..255
    const int bimg  = strip >> 4;        // 0..15
    const int r0    = (strip & 15) << 6;
    const int c0    = c0i << 6;

    const int t = threadIdx.x;           // 0..511

    const unsigned char* __restrict__ inb =
        (const unsigned char*)in + (size_t)bimg * (size_t)(NDIM * ROWB);
    unsigned char* __restrict__ outb =
        (unsigned char*)out + (size_t)bimg * (size_t)(NDIM * ROWB);

    // ---- phase 1: global -> LDS. 64 segments x 768B = 3072 chunks of 16B.
#pragma unroll
    for (int kk = 0; kk < 6; ++kk) {
        const int chunk = t + 512 * kk;          // 0..3071
        const int seg   = chunk / 48;            // 0..63 (magic-div)
        const int off16 = (chunk - seg * 48) << 4;  // 0..752
        const int c     = c0 + seg;
        const int R     = (169 * c) & MASKN;
        const int col0  = (r0 + 239 * c) & MASKN;
        const unsigned  wb   = (unsigned)col0 * 12u;
        const unsigned  o    = wb + (unsigned)off16;
        const unsigned char* __restrict__ rowp = inb + (size_t)R * ROWB;
        unsigned char* __restrict__ dst = &lds[seg * PITCHB + off16];

        if (o < (unsigned)ROWB && o + 16u > (unsigned)ROWB) {
            // chunk straddles the circular row boundary: dword-granular
#pragma unroll
            for (int g = 0; g < 4; ++g) {
                unsigned oo = o + 4u * g;
                if (oo >= (unsigned)ROWB) oo -= (unsigned)ROWB;
                *(float*)(dst + 4 * g) = *(const float*)(rowp + oo);
            }
        } else {
            const unsigned oo = (o >= (unsigned)ROWB) ? o - (unsigned)ROWB : o;
            const f4u v = *(const f4u*)(rowp + oo);
            // LDS dest only 4B-aligned in general: store as dwords
            *(float*)(dst +  0) = v[0];
            *(float*)(dst +  4) = v[1];
            *(float*)(dst +  8) = v[2];
            *(float*)(dst + 12) = v[3];
        }
    }
    __syncthreads();

    // ---- phase 2: LDS -> global. 64 output runs x 768B = 3072 chunks of 16B.
#pragma unroll
    for (int kk = 0; kk < 6; ++kk) {
        const int chunk = t + 512 * kk;          // 0..3071
        const int r     = chunk / 48;            // 0..63
        const int off16 = (chunk - r * 48) << 4; // 0..752
        const int i     = (169 * (r0 + r)) & MASKN;
        const int j0    = (c0 + 41 * i) & MASKN;
        const unsigned  ob = (unsigned)j0 * 12u + (unsigned)off16;
        unsigned char* __restrict__ orow = outb + (size_t)i * ROWB;

        float v[4];
#pragma unroll
        for (int g = 0; g < 4; ++g) {
            const int b  = off16 + 4 * g;        // byte within 768B run
            const int cp = (b * 2731) >> 15;     // b / 12  (valid for b < 768+12)
            const int e  = b - 12 * cp;          // b % 12
            v[g] = *(const float*)&lds[cp * PITCHB + r * 12 + e];
        }

        if (ob < (unsigned)ROWB && ob + 16u > (unsigned)ROWB) {
#pragma unroll
            for (int g = 0; g < 4; ++g) {
                unsigned oo = ob + 4u * g;
                if (oo >= (unsigned)ROWB) oo -= (unsigned)ROWB;
                *(float*)(orow + oo) = v[g];
            }
        } else {
            const unsigned oo = (ob >= (unsigned)ROWB) ? ob - (unsigned)ROWB : ob;
            f4u w; w[0] = v[0]; w[1] = v[1]; w[2] = v[2]; w[3] = v[3];
            *(f4u*)(orow + oo) = w;
        }
    }
}

extern "C" void kernel_launch(void* const* d_in, const int* in_sizes, int n_in,
                              void* d_out, int out_size, void* d_ws, size_t ws_size,
                              hipStream_t stream) {
    (void)in_sizes; (void)n_in; (void)d_ws; (void)ws_size; (void)out_size;
    const float* in = (const float*)d_in[0];
    float* out      = (float*)d_out;
    dim3 grid(4096, 1, 1);   // 16 batches x 16x16 tiles
    dim3 block(512, 1, 1);
    hipLaunchKernelGGL(arnold_cat7_kernel, grid, block, 0, stream, in, out);
}

// Round 3
// 332.586 us; speedup vs baseline: 1.0288x; 1.0090x over previous
//
#include <hip/hip_runtime.h>

// Arnold cat, 7 iterations fused: out[b,i,j,:] = in[b, (239i+169j)%1024, (338i+239j)%1024, :]
// Round 3: occupancy experiment. Identical index math / LDS byte-image /
// chunked dwordx4 copy vehicle as the absmax=0-verified round-2 kernel; the
// only change is tile c-extent 64 -> 32 segments:
//   LDS 49408 B -> 24704 B  => 4 blocks/CU (2048-thread cap) = 32 waves/CU,
//   up from 3 blocks / 24 waves. Grid 4096 -> 8192 blocks.
// Read runs stay 768 B (r-extent 64); write runs become 384 B (proven
// irrelevant: rounds 0-1 varied write runs 768->192 B with no effect).

#define NDIM    1024
#define MASKN   1023
#define ROWB    12288            // bytes per image row (1024 px * 12 B)
#define SEGS    32               // tile c-extent (segments per block)
#define PITCHB  772              // LDS bytes per segment: 768 + 4 (193 dwords, odd)

typedef float f4u __attribute__((ext_vector_type(4), aligned(4)));

__global__ __launch_bounds__(512, 8) void arnold_cat7_kernel(
    const float* __restrict__ in, float* __restrict__ out) {
    __shared__ alignas(16) unsigned char lds[SEGS * PITCHB];  // 24704 B -> 4 blocks/CU

    // ---- block swizzle: B -> (batch, r0, c0); same-(batch,r0) strips pinned
    // to one XCD (c0 fastest-varying there) so partial lines merge in its L2.
    const int B     = blockIdx.x;        // 0..8191
    const int xcd   = B & 7;
    const int q     = B >> 3;            // 0..1023
    const int c0i   = q & 31;            // 32 c-tiles per strip
    const int strip = ((q >> 5) << 3) | xcd;  // 0..255
    const int bimg  = strip >> 4;        // 0..15
    const int r0    = (strip & 15) << 6; // 0..960 step 64
    const int c0    = c0i << 5;          // 0..992 step 32

    const int t = threadIdx.x;           // 0..511

    const unsigned char* __restrict__ inb =
        (const unsigned char*)in + (size_t)bimg * (size_t)(NDIM * ROWB);
    unsigned char* __restrict__ outb =
        (unsigned char*)out + (size_t)bimg * (size_t)(NDIM * ROWB);

    // ---- phase 1: global -> LDS. 32 segments x 768B = 1536 chunks of 16B.
#pragma unroll
    for (int kk = 0; kk < 3; ++kk) {
        const int chunk = t + 512 * kk;          // 0..1535
        const int seg   = chunk / 48;            // 0..31 (magic-div)
        const int off16 = (chunk - seg * 48) << 4;  // 0..752
        const int c     = c0 + seg;
        const int R     = (169 * c) & MASKN;
        const int col0  = (r0 + 239 * c) & MASKN;
        const unsigned  o = (unsigned)col0 * 12u + (unsigned)off16;
        const unsigned char* __restrict__ rowp = inb + (size_t)R * ROWB;
        unsigned char* __restrict__ dst = &lds[seg * PITCHB + off16];

        if (o < (unsigned)ROWB && o + 16u > (unsigned)ROWB) {
            // chunk straddles the circular row boundary: dword-granular
#pragma unroll
            for (int g = 0; g < 4; ++g) {
                unsigned oo = o + 4u * g;
                if (oo >= (unsigned)ROWB) oo -= (unsigned)ROWB;
                *(float*)(dst + 4 * g) = *(const float*)(rowp + oo);
            }
        } else {
            const unsigned oo = (o >= (unsigned)ROWB) ? o - (unsigned)ROWB : o;
            const f4u v = *(const f4u*)(rowp + oo);
            *(float*)(dst +  0) = v[0];
            *(float*)(dst +  4) = v[1];
            *(float*)(dst +  8) = v[2];
            *(float*)(dst + 12) = v[3];
        }
    }
    __syncthreads();

    // ---- phase 2: LDS -> global. 64 output rows x 384B = 1536 chunks of 16B.
#pragma unroll
    for (int kk = 0; kk < 3; ++kk) {
        const int chunk = t + 512 * kk;          // 0..1535
        const int r     = chunk / 24;            // 0..63
        const int off16 = (chunk - r * 24) << 4; // 0..368
        const int i     = (169 * (r0 + r)) & MASKN;
        const int j0    = (c0 + 41 * i) & MASKN;
        const unsigned  ob = (unsigned)j0 * 12u + (unsigned)off16;
        unsigned char* __restrict__ orow = outb + (size_t)i * ROWB;

        float v[4];
#pragma unroll
        for (int g = 0; g < 4; ++g) {
            const int b  = off16 + 4 * g;        // byte within 384B run
            const int cp = (b * 2731) >> 15;     // b / 12
            const int e  = b - 12 * cp;          // b % 12
            v[g] = *(const float*)&lds[cp * PITCHB + r * 12 + e];
        }

        if (ob < (unsigned)ROWB && ob + 16u > (unsigned)ROWB) {
#pragma unroll
            for (int g = 0; g < 4; ++g) {
                unsigned oo = ob + 4u * g;
                if (oo >= (unsigned)ROWB) oo -= (unsigned)ROWB;
                *(float*)(orow + oo) = v[g];
            }
        } else {
            const unsigned oo = (ob >= (unsigned)ROWB) ? ob - (unsigned)ROWB : ob;
            f4u w; w[0] = v[0]; w[1] = v[1]; w[2] = v[2]; w[3] = v[3];
            *(f4u*)(orow + oo) = w;
        }
    }
}

extern "C" void kernel_launch(void* const* d_in, const int* in_sizes, int n_in,
                              void* d_out, int out_size, void* d_ws, size_t ws_size,
                              hipStream_t stream) {
    (void)in_sizes; (void)n_in; (void)d_ws; (void)ws_size; (void)out_size;
    const float* in = (const float*)d_in[0];
    float* out      = (float*)d_out;
    dim3 grid(8192, 1, 1);   // 16 batches x 16 r-strips x 32 c-tiles
    dim3 block(512, 1, 1);
    hipLaunchKernelGGL(arnold_cat7_kernel, grid, block, 0, stream, in, out);
}